// Round 11
// baseline (554.485 us; speedup 1.0000x reference)
//
#include <hip/hip_runtime.h>
#include <hip/hip_bf16.h>
#include <hip/hip_cooperative_groups.h>
#include <stdint.h>

namespace cg = cooperative_groups;

using bf16 = __hip_bfloat16;
typedef __attribute__((ext_vector_type(8))) short bf16x8;
typedef __attribute__((ext_vector_type(4))) float f32x4;

// ---------------------------------------------------------------------------
// helpers
// ---------------------------------------------------------------------------
__device__ __forceinline__ void gload_lds16(const void* g, void* l) {
  __builtin_amdgcn_global_load_lds(
      (__attribute__((address_space(1))) void*)(g),
      (__attribute__((address_space(3))) void*)(l), 16, 0, 0);
}

__device__ __forceinline__ unsigned short bf16_bits(float f) {
  bf16 b = __float2bfloat16(f);
  return *reinterpret_cast<unsigned short*>(&b);
}

__device__ __forceinline__ float b2f(unsigned short u) {
  union { unsigned int i; float f; } x;
  x.i = ((unsigned int)u) << 16;
  return x.f;
}

// ---------------------------------------------------------------------------
// pre_all: grid (16, 176).  (unchanged from R8)
// ---------------------------------------------------------------------------
__global__ __launch_bounds__(256) void pre_all(
    const float* __restrict__ x, const float* __restrict__ Wq,
    const float* __restrict__ Wk, const float* __restrict__ Wv,
    unsigned short* __restrict__ xb, unsigned short* __restrict__ xt,
    float* __restrict__ part, unsigned short* __restrict__ Wqx2,
    unsigned short* __restrict__ Wkext, unsigned short* __restrict__ Wvtb) {
  __shared__ unsigned short tile[64][79];
  __shared__ float cw[4][64];
  const int by = blockIdx.y;
  const int c0 = blockIdx.x * 64;
  const int tr = threadIdx.x >> 4;         // 0..15
  const int tc4 = (threadIdx.x & 15) * 4;  // 0,4,..,60

  if (by < 128) {
    const int r0 = by * 64;
    float ca0 = 0.f, ca1 = 0.f, ca2 = 0.f, ca3 = 0.f;
#pragma unroll
    for (int p = 0; p < 4; ++p) {
      const int r = p * 16 + tr;
      float4 f =
          *reinterpret_cast<const float4*>(x + (size_t)(r0 + r) * 1024 + c0 + tc4);
      unsigned short u0 = bf16_bits(f.x), u1 = bf16_bits(f.y);
      unsigned short u2 = bf16_bits(f.z), u3 = bf16_bits(f.w);
      ushort4 u = {u0, u1, u2, u3};
      *reinterpret_cast<ushort4*>(xb + (size_t)(r0 + r) * 1024 + c0 + tc4) = u;
      tile[r][tc4] = u0;
      tile[r][tc4 + 1] = u1;
      tile[r][tc4 + 2] = u2;
      tile[r][tc4 + 3] = u3;
      ca0 += f.x;
      ca1 += f.y;
      ca2 += f.z;
      ca3 += f.w;
    }
    ca0 += __shfl_xor(ca0, 16); ca0 += __shfl_xor(ca0, 32);
    ca1 += __shfl_xor(ca1, 16); ca1 += __shfl_xor(ca1, 32);
    ca2 += __shfl_xor(ca2, 16); ca2 += __shfl_xor(ca2, 32);
    ca3 += __shfl_xor(ca3, 16); ca3 += __shfl_xor(ca3, 32);
    const int lane = threadIdx.x & 63, wv = threadIdx.x >> 6;
    if (lane < 16) {
      cw[wv][lane * 4] = ca0;
      cw[wv][lane * 4 + 1] = ca1;
      cw[wv][lane * 4 + 2] = ca2;
      cw[wv][lane * 4 + 3] = ca3;
    }
    __syncthreads();
    if (threadIdx.x < 64) {
      float s = cw[0][threadIdx.x] + cw[1][threadIdx.x] + cw[2][threadIdx.x] +
                cw[3][threadIdx.x];
      part[(size_t)by * 1024 + c0 + threadIdx.x] = s;
    }
#pragma unroll
    for (int p = 0; p < 4; ++p) {
      const int c = p * 16 + tr;
      ushort4 u = {tile[tc4][c], tile[tc4 + 1][c], tile[tc4 + 2][c],
                   tile[tc4 + 3][c]};
      *reinterpret_cast<ushort4*>(xt + (size_t)(c0 + c) * 8192 + r0 + tc4) = u;
    }
  } else {
    const int w = by - 128;
    const int widx = w >> 4;          // 0=Wq,1=Wk,2=Wv
    const int r0 = (w & 15) * 64;
    if (widx < 2) {
      const float* W = (widx == 0) ? Wq : Wk;
      unsigned short* out = (widx == 0) ? Wqx2 : Wkext;
#pragma unroll
      for (int p = 0; p < 4; ++p) {
        const int r = r0 + p * 16 + tr;
        float4 f =
            *reinterpret_cast<const float4*>(W + (size_t)r * 1024 + c0 + tc4);
        ushort4 u = {bf16_bits(f.x), bf16_bits(f.y), bf16_bits(f.z),
                     bf16_bits(f.w)};
        *reinterpret_cast<ushort4*>(out + (size_t)r * 2048 + c0 + tc4) = u;
        *reinterpret_cast<ushort4*>(out + (size_t)r * 2048 + 1024 + c0 + tc4) = u;
      }
    } else {
#pragma unroll
      for (int p = 0; p < 4; ++p) {
        const int r = p * 16 + tr;
        float4 f = *reinterpret_cast<const float4*>(Wv + (size_t)(r0 + r) * 1024 +
                                                    c0 + tc4);
        tile[r][tc4] = bf16_bits(f.x);
        tile[r][tc4 + 1] = bf16_bits(f.y);
        tile[r][tc4 + 2] = bf16_bits(f.z);
        tile[r][tc4 + 3] = bf16_bits(f.w);
      }
      __syncthreads();
#pragma unroll
      for (int p = 0; p < 4; ++p) {
        const int c = p * 16 + tr;
        ushort4 u = {tile[tc4][c], tile[tc4 + 1][c], tile[tc4 + 2][c],
                     tile[tc4 + 3][c]};
        *reinterpret_cast<ushort4*>(Wvtb + (size_t)(c0 + c) * 1024 + r0 + tc4) = u;
      }
    }
  }
}

// ---------------------------------------------------------------------------
// NT GEMM, 2-phase double-buffered 128x128 (unchanged from R8): G (TRI) + out.
// ---------------------------------------------------------------------------
template <int BIAS_MODE, int OUT_BF16, int XCD_SWZ, int CONCAT, int TRI>
__global__ __launch_bounds__(256, 2) void gemm_nt(
    const bf16* __restrict__ A, const bf16* __restrict__ B,
    const float* __restrict__ bias, void* __restrict__ Cout, int M, int N,
    int K, int kChunk, float scale) {
  __shared__ __align__(128) char lds[65536];  // A: [2][16KB] @0, B: @32768
  const int tid = threadIdx.x;
  const int lane = tid & 63;
  const int wv = tid >> 6;
  const int wm = wv >> 1, wn = wv & 1;

  int mt, nt, zz;
  if (TRI) {
    const int lin = blockIdx.x;
    zz = lin & 7;            // one K-chunk per XCD
    const int p = lin >> 3;  // 0..35 triangle pair
    int ii = 0;
    while ((ii + 1) * (ii + 2) / 2 <= p) ++ii;
    mt = ii;
    nt = p - ii * (ii + 1) / 2;
  } else if (XCD_SWZ) {
    int lin = blockIdx.y * gridDim.x + blockIdx.x;
    int cpx = (gridDim.x * gridDim.y) >> 3;  // nwg % 8 == 0 required
    int swz = (lin & 7) * cpx + (lin >> 3);
    nt = swz % gridDim.x;
    mt = swz / gridDim.x;
    zz = blockIdx.z;
  } else {
    nt = blockIdx.x;
    mt = blockIdx.y;
    zz = blockIdx.z;
  }
  const int m0 = mt * 128, n0 = nt * 128;
  const int kBegin = zz * kChunk;

  const char* srcA[4];
  const char* srcB[4];
  int dstOff[4];
#pragma unroll
  for (int t = 0; t < 4; ++t) {
    int o = wv * 4096 + t * 1024 + lane * 16;  // linear LDS byte offset
    int row = o >> 7;                          // tile row (128B per row)
    int gcb = (o & 127) ^ ((row & 7) << 4);    // inverse-swizzled global col
    srcA[t] = (const char*)A + ((size_t)(m0 + row) * K + kBegin) * 2 + gcb;
    srcB[t] = (const char*)B + ((size_t)(n0 + row) * K + kBegin) * 2 + gcb;
    dstOff[t] = wv * 4096 + t * 1024;
  }

  const int xorv = (lane & 7) << 4;
  const int rowOff = (lane & 15) * 128;
  const int colHi = (lane >> 4) << 4;

  // prologue: stage tile 0 into buf 0
#pragma unroll
  for (int t = 0; t < 4; ++t) gload_lds16(srcA[t], lds + dstOff[t]);
#pragma unroll
  for (int t = 0; t < 4; ++t) gload_lds16(srcB[t], lds + 32768 + dstOff[t]);
#pragma unroll
  for (int t = 0; t < 4; ++t) {
    srcA[t] += 128;
    srcB[t] += 128;
  }
  __syncthreads();

  f32x4 acc[4][4] = {};
  const int nk = kChunk >> 6;
  int cur = 0;
  for (int kt = 0; kt < nk; ++kt) {
    if (kt + 1 < nk) {  // prefetch next tile into the other buffer
      const int nb = (cur ^ 1) * 16384;
#pragma unroll
      for (int t = 0; t < 4; ++t) gload_lds16(srcA[t], lds + nb + dstOff[t]);
#pragma unroll
      for (int t = 0; t < 4; ++t)
        gload_lds16(srcB[t], lds + 32768 + nb + dstOff[t]);
#pragma unroll
      for (int t = 0; t < 4; ++t) {
        srcA[t] += 128;
        srcB[t] += 128;
      }
    }
    const char* baseA = lds + cur * 16384;
    const char* baseB = lds + 32768 + cur * 16384;
#pragma unroll
    for (int h = 0; h < 2; ++h) {
      const int kk64 = h * 64;
      bf16x8 af[4], bfr[4];
#pragma unroll
      for (int f = 0; f < 4; ++f)
        af[f] = *reinterpret_cast<const bf16x8*>(
            baseA + ((wm * 64 + f * 16) * 128) + rowOff + ((kk64 + colHi) ^ xorv));
#pragma unroll
      for (int f = 0; f < 4; ++f)
        bfr[f] = *reinterpret_cast<const bf16x8*>(
            baseB + ((wn * 64 + f * 16) * 128) + rowOff + ((kk64 + colHi) ^ xorv));
      __builtin_amdgcn_s_setprio(1);
#pragma unroll
      for (int m = 0; m < 4; ++m)
#pragma unroll
        for (int n = 0; n < 4; ++n)
          acc[m][n] = __builtin_amdgcn_mfma_f32_16x16x32_bf16(af[m], bfr[n],
                                                              acc[m][n], 0, 0, 0);
      __builtin_amdgcn_s_setprio(0);
    }
    __syncthreads();  // staged loads drained; all waves done reading cur
    cur ^= 1;
  }

  // epilogue: C/D layout col=lane&15, row=(lane>>4)*4+r (guide §3, m89)
  const int ldC = CONCAT ? (int)(gridDim.z * N) : N;
  const int cOff = CONCAT ? (int)(zz * N) : 0;
  char* Cbase = (char*)Cout;
  if (!CONCAT) Cbase += (size_t)zz * M * N * (OUT_BF16 ? 2 : 4);
#pragma unroll
  for (int m = 0; m < 4; ++m) {
    const int grow = m0 + wm * 64 + m * 16 + ((lane >> 4) << 2);
#pragma unroll
    for (int n = 0; n < 4; ++n) {
      const int gcol = n0 + wn * 64 + n * 16 + (lane & 15);
#pragma unroll
      for (int r = 0; r < 4; ++r) {
        float v = acc[m][n][r] * scale;
        if (BIAS_MODE == 2) v += bias[gcol];
        if (OUT_BF16)
          ((bf16*)Cbase)[(size_t)(grow + r) * ldC + cOff + gcol] =
              __float2bfloat16(v);
        else
          ((float*)Cbase)[(size_t)(grow + r) * ldC + cOff + gcol] = v;
      }
    }
  }
}

// ---------------------------------------------------------------------------
// 64x64 NT GEMM body (single-buffer 16KB LDS) as a device function.
// ZCAT: 1 -> C[row][zz*N+col], ld gridZ*N (bf16 col-concat partials).
// ---------------------------------------------------------------------------
template <int OUT_BF16, int ZCAT>
__device__ __forceinline__ void gemm64_body(const bf16* A, const bf16* B,
                                            void* Cout, int M, int N, int K,
                                            int kBegin, int kChunk, int mt,
                                            int nt, int zz, int gridZ,
                                            float scale, char* lds) {
  const int tid = threadIdx.x;
  const int lane = tid & 63;
  const int wv = tid >> 6;
  const int wm = wv >> 1, wn = wv & 1;
  const int m0 = mt * 64, n0 = nt * 64;

  const char* srcA[2];
  const char* srcB[2];
  int dstOff[2];
#pragma unroll
  for (int t = 0; t < 2; ++t) {
    int o = wv * 2048 + t * 1024 + lane * 16;  // linear LDS byte offset
    int row = o >> 7;                          // tile row (128B per row)
    int gcb = (o & 127) ^ ((row & 7) << 4);    // inverse-swizzled global col
    srcA[t] = (const char*)A + ((size_t)(m0 + row) * K + kBegin) * 2 + gcb;
    srcB[t] = (const char*)B + ((size_t)(n0 + row) * K + kBegin) * 2 + gcb;
    dstOff[t] = wv * 2048 + t * 1024;
  }

  const int xorv = (lane & 7) << 4;
  const int rowOff = (lane & 15) * 128;
  const int colHi = (lane >> 4) << 4;

  f32x4 acc[2][2] = {};
  const int nk = kChunk >> 6;
  for (int kt = 0; kt < nk; ++kt) {
#pragma unroll
    for (int t = 0; t < 2; ++t) gload_lds16(srcA[t], lds + dstOff[t]);
#pragma unroll
    for (int t = 0; t < 2; ++t) gload_lds16(srcB[t], lds + 8192 + dstOff[t]);
#pragma unroll
    for (int t = 0; t < 2; ++t) {
      srcA[t] += 128;
      srcB[t] += 128;
    }
    __syncthreads();
#pragma unroll
    for (int h = 0; h < 2; ++h) {
      const int kk64 = h * 64;
      bf16x8 af[2], bfr[2];
#pragma unroll
      for (int f = 0; f < 2; ++f)
        af[f] = *reinterpret_cast<const bf16x8*>(
            lds + ((wm * 32 + f * 16) * 128) + rowOff + ((kk64 + colHi) ^ xorv));
#pragma unroll
      for (int f = 0; f < 2; ++f)
        bfr[f] = *reinterpret_cast<const bf16x8*>(
            lds + 8192 + ((wn * 32 + f * 16) * 128) + rowOff +
            ((kk64 + colHi) ^ xorv));
      __builtin_amdgcn_s_setprio(1);
#pragma unroll
      for (int m = 0; m < 2; ++m)
#pragma unroll
        for (int n = 0; n < 2; ++n)
          acc[m][n] = __builtin_amdgcn_mfma_f32_16x16x32_bf16(af[m], bfr[n],
                                                              acc[m][n], 0, 0, 0);
      __builtin_amdgcn_s_setprio(0);
    }
    __syncthreads();
  }

  const int ldC = ZCAT ? gridZ * N : N;
  const int cOff = ZCAT ? zz * N : 0;
  char* Cbase = (char*)Cout;
  if (!ZCAT) Cbase += (size_t)zz * M * N * (OUT_BF16 ? 2 : 4);
#pragma unroll
  for (int m = 0; m < 2; ++m) {
    const int grow = m0 + wm * 32 + m * 16 + ((lane >> 4) << 2);
#pragma unroll
    for (int n = 0; n < 2; ++n) {
      const int gcol = n0 + wn * 32 + n * 16 + (lane & 15);
#pragma unroll
      for (int r = 0; r < 4; ++r) {
        float v = acc[m][n][r] * scale;
        if (OUT_BF16)
          ((bf16*)Cbase)[(size_t)(grow + r) * ldC + cOff + gcol] =
              __float2bfloat16(v);
        else
          ((float*)Cbase)[(size_t)(grow + r) * ldC + cOff + gcol] = v;
      }
    }
  }
}

// ---------------------------------------------------------------------------
// Shared phase bodies (used by both the cooperative kernel and the fallback
// standalone kernels — bit-identical math either way).
// ---------------------------------------------------------------------------
__device__ __forceinline__ void phase_gext(const float* Sp,
                                           unsigned short* Gext, int bx,
                                           int tid, char* shmem) {
  float(*tf)[65] = reinterpret_cast<float(*)[65]>(shmem);
  const int ti = bx >> 4, tj = bx & 15;
  const bool mirror = (ti >> 1) < (tj >> 1);
  const int si = mirror ? tj : ti, sj = mirror ? ti : tj;
  const int r = tid >> 4, c4 = (tid & 15) * 4;
#pragma unroll
  for (int pass = 0; pass < 4; ++pass) {
    const int row = pass * 16 + r;
    float g0 = 0.f, g1 = 0.f, g2 = 0.f, g3 = 0.f;
#pragma unroll
    for (int z = 0; z < 8; ++z) {
      float4 f = *reinterpret_cast<const float4*>(
          Sp + ((size_t)z << 20) + (size_t)(si * 64 + row) * 1024 + sj * 64 + c4);
      g0 += f.x;
      g1 += f.y;
      g2 += f.z;
      g3 += f.w;
    }
    if (!mirror) {
      ushort4 hi, lo;
      unsigned short bb;
      bb = bf16_bits(g0); hi.x = bb; lo.x = bf16_bits(g0 - b2f(bb));
      bb = bf16_bits(g1); hi.y = bb; lo.y = bf16_bits(g1 - b2f(bb));
      bb = bf16_bits(g2); hi.z = bb; lo.z = bf16_bits(g2 - b2f(bb));
      bb = bf16_bits(g3); hi.w = bb; lo.w = bf16_bits(g3 - b2f(bb));
      const size_t base = (size_t)(ti * 64 + row) * 2048 + tj * 64 + c4;
      *reinterpret_cast<ushort4*>(Gext + base) = hi;
      *reinterpret_cast<ushort4*>(Gext + base + 1024) = lo;
    } else {
      tf[row][c4] = g0;
      tf[row][c4 + 1] = g1;
      tf[row][c4 + 2] = g2;
      tf[row][c4 + 3] = g3;
    }
  }
  if (mirror) {
    __syncthreads();
#pragma unroll
    for (int pass = 0; pass < 4; ++pass) {
      const int crow = pass * 16 + r;
      ushort4 hi, lo;
      unsigned short bb;
      float g;
      g = tf[c4][crow];     bb = bf16_bits(g); hi.x = bb; lo.x = bf16_bits(g - b2f(bb));
      g = tf[c4 + 1][crow]; bb = bf16_bits(g); hi.y = bb; lo.y = bf16_bits(g - b2f(bb));
      g = tf[c4 + 2][crow]; bb = bf16_bits(g); hi.z = bb; lo.z = bf16_bits(g - b2f(bb));
      g = tf[c4 + 3][crow]; bb = bf16_bits(g); hi.w = bb; lo.w = bf16_bits(g - b2f(bb));
      const size_t base = (size_t)(ti * 64 + crow) * 2048 + tj * 64 + c4;
      *reinterpret_cast<ushort4*>(Gext + base) = hi;
      *reinterpret_cast<ushort4*>(Gext + base + 1024) = lo;
    }
  }
}

__device__ __forceinline__ void phase_svuw(const float* part, const float* Wq,
                                           const float* Wk, float* uw, int bxm,
                                           int tid, char* shmem) {
  float* svl = reinterpret_cast<float*>(shmem);
  float4 a = {0.f, 0.f, 0.f, 0.f};
  for (int p = 0; p < 128; ++p) {
    float4 f = *reinterpret_cast<const float4*>(part + (size_t)p * 1024 + tid * 4);
    a.x += f.x;
    a.y += f.y;
    a.z += f.z;
    a.w += f.w;
  }
  *reinterpret_cast<float4*>(svl + tid * 4) = a;
  __syncthreads();
  const int lane = tid & 63, wv = tid >> 6;
  const int lane16 = lane & 15, rsub = lane >> 4;
  const int row = bxm * 16 + wv * 4 + rsub;
  const float* W = (row < 1024) ? (Wq + (size_t)row * 1024)
                                : (Wk + (size_t)(row - 1024) * 1024);
  float acc = 0.f;
#pragma unroll
  for (int q = 0; q < 16; ++q) {
    const int c = (lane16 + q * 16) * 4;
    float4 wv4 = *reinterpret_cast<const float4*>(W + c);
    float4 s4 = *reinterpret_cast<const float4*>(svl + c);
    acc += wv4.x * s4.x + wv4.y * s4.y + wv4.z * s4.z + wv4.w * s4.w;
  }
#pragma unroll
  for (int off = 1; off < 16; off <<= 1) acc += __shfl_xor(acc, off);
  if (lane16 == 0) uw[row] = acc;
}

__device__ __forceinline__ void phase_softmax(const float* Stp, const float* uw,
                                              const float* bq, const float* bk,
                                              const float* bv, bf16* At,
                                              float* rv, int j, int tid,
                                              float* red) {
  const int lane = tid & 63, wv = tid >> 6;
  __syncthreads();  // protect red[] reuse across consecutive rows
  const float a1 = bk[j];
  const float a2 = uw[1024 + j] + 8192.0f * a1;
  const float norm = 0.03125f;  // 1/sqrt(1024)
  float v[4];
#pragma unroll
  for (int t = 0; t < 4; ++t) {
    const int i = tid + 256 * t;
    float s = Stp[(size_t)j * 1024 + i] + Stp[(1ull << 20) + (size_t)j * 1024 + i];
    v[t] = norm * (s + a1 * uw[i] + a2 * bq[i]);
  }
  float m = fmaxf(fmaxf(v[0], v[1]), fmaxf(v[2], v[3]));
#pragma unroll
  for (int off = 32; off; off >>= 1) m = fmaxf(m, __shfl_xor(m, off));
  if (lane == 0) red[wv] = m;
  __syncthreads();
  m = fmaxf(fmaxf(red[0], red[1]), fmaxf(red[2], red[3]));
  float p[4], s = 0.f, pr = 0.f;
#pragma unroll
  for (int t = 0; t < 4; ++t) {
    p[t] = __expf(v[t] - m);
    s += p[t];
    pr += p[t] * bv[tid + 256 * t];
  }
#pragma unroll
  for (int off = 32; off; off >>= 1) {
    s += __shfl_xor(s, off);
    pr += __shfl_xor(pr, off);
  }
  if (lane == 0) {
    red[4 + wv] = s;
    red[8 + wv] = pr;
  }
  __syncthreads();
  const float inv = 1.f / (red[4] + red[5] + red[6] + red[7]);
#pragma unroll
  for (int t = 0; t < 4; ++t)
    At[(size_t)j * 1024 + tid + 256 * t] = __float2bfloat16(p[t] * inv);
  if (tid == 0) rv[j] = (red[8] + red[9] + red[10] + red[11]) * inv;
}

// ---------------------------------------------------------------------------
// Cooperative middle kernel (grid 512 x 256): A -> B -> C -> D -> E with
// grid.sync() between phases. Phase math == fallback kernels below.
// ---------------------------------------------------------------------------
__global__ __launch_bounds__(256) void coop_mid(
    const float* __restrict__ Sp, unsigned short* __restrict__ Gext,
    const float* __restrict__ part, const float* __restrict__ Wq,
    const float* __restrict__ Wk, float* __restrict__ uw,
    const bf16* __restrict__ Wkext, bf16* __restrict__ T1x,
    const bf16* __restrict__ Wqx2, float* __restrict__ Stp,
    const float* __restrict__ bq, const float* __restrict__ bk,
    const float* __restrict__ bv, bf16* __restrict__ At,
    float* __restrict__ rv, const bf16* __restrict__ Wvtb,
    bf16* __restrict__ Ftb) {
  __shared__ __align__(128) char shmem[16640];
  cg::grid_group grid = cg::this_grid();
  const int bx = blockIdx.x;
  const int tid = threadIdx.x;

  // Phase A
  if (bx < 256)
    phase_gext(Sp, Gext, bx, tid, shmem);
  else if (bx < 384)
    phase_svuw(part, Wq, Wk, uw, bx - 256, tid, shmem);
  __threadfence();
  grid.sync();

  // Phase B: T1 = Wk*G (bf16 col-concat)
  {
    const int z = bx >> 8;
    const int lin = bx & 255;
    const int swz = (lin & 7) * 32 + (lin >> 3);
    gemm64_body<1, 1>(Wkext, (const bf16*)Gext, T1x, 1024, 1024, 2048,
                      z * 1024, 1024, swz >> 4, swz & 15, z, 2, 1.0f, shmem);
  }
  __threadfence();
  grid.sync();

  // Phase C: St = T1x * Wqx2^T (f32 partials)
  {
    const int z = bx >> 8;
    const int lin = bx & 255;
    const int swz = (lin & 7) * 32 + (lin >> 3);
    gemm64_body<0, 0>(T1x, Wqx2, Stp, 1024, 1024, 2048, z * 1024, 1024,
                      swz >> 4, swz & 15, z, 2, 1.0f, shmem);
  }
  __threadfence();
  grid.sync();

  // Phase D: softmax + r (2 rows per block)
  {
    float* red = reinterpret_cast<float*>(shmem);
    phase_softmax(Stp, uw, bq, bk, bv, At, rv, bx * 2, tid, red);
    phase_softmax(Stp, uw, bq, bk, bv, At, rv, bx * 2 + 1, tid, red);
  }
  __threadfence();
  grid.sync();

  // Phase E: F^T = At * Wvt^T
  if (bx < 256) {
    const int swz = (bx & 7) * 32 + (bx >> 3);
    gemm64_body<1, 0>(At, Wvtb, Ftb, 1024, 1024, 1024, 0, 1024, swz >> 4,
                      swz & 15, 0, 1, 1.0f, shmem);
  }
}

// ---------------------------------------------------------------------------
// Fallback standalone kernels (R8-equivalent node chain, same phase bodies)
// ---------------------------------------------------------------------------
__global__ __launch_bounds__(256) void k_gext_svuw(
    const float* __restrict__ Sp, unsigned short* __restrict__ Gext,
    const float* __restrict__ part, const float* __restrict__ Wq,
    const float* __restrict__ Wk, float* __restrict__ uw) {
  __shared__ __align__(128) char shmem[16640];
  if (blockIdx.x < 256)
    phase_gext(Sp, Gext, blockIdx.x, threadIdx.x, shmem);
  else
    phase_svuw(part, Wq, Wk, uw, blockIdx.x - 256, threadIdx.x, shmem);
}

__global__ __launch_bounds__(256, 4) void k_t1(const bf16* __restrict__ Wkext,
                                               const bf16* __restrict__ Gext,
                                               bf16* __restrict__ T1x) {
  __shared__ __align__(128) char shmem[16384];
  const int z = blockIdx.x >> 8;
  const int lin = blockIdx.x & 255;
  const int swz = (lin & 7) * 32 + (lin >> 3);
  gemm64_body<1, 1>(Wkext, Gext, T1x, 1024, 1024, 2048, z * 1024, 1024,
                    swz >> 4, swz & 15, z, 2, 1.0f, shmem);
}

__global__ __launch_bounds__(256, 4) void k_st(const bf16* __restrict__ T1x,
                                               const bf16* __restrict__ Wqx2,
                                               float* __restrict__ Stp) {
  __shared__ __align__(128) char shmem[16384];
  const int z = blockIdx.x >> 8;
  const int lin = blockIdx.x & 255;
  const int swz = (lin & 7) * 32 + (lin >> 3);
  gemm64_body<0, 0>(T1x, Wqx2, Stp, 1024, 1024, 2048, z * 1024, 1024, swz >> 4,
                    swz & 15, z, 2, 1.0f, shmem);
}

__global__ __launch_bounds__(256) void k_softmax(
    const float* __restrict__ Stp, const float* __restrict__ uw,
    const float* __restrict__ bq, const float* __restrict__ bk,
    const float* __restrict__ bv, bf16* __restrict__ At,
    float* __restrict__ rv) {
  __shared__ float red[12];
  phase_softmax(Stp, uw, bq, bk, bv, At, rv, blockIdx.x * 2, threadIdx.x, red);
  phase_softmax(Stp, uw, bq, bk, bv, At, rv, blockIdx.x * 2 + 1, threadIdx.x,
                red);
}

__global__ __launch_bounds__(256, 4) void k_f(const bf16* __restrict__ At,
                                              const bf16* __restrict__ Wvtb,
                                              bf16* __restrict__ Ftb) {
  __shared__ __align__(128) char shmem[16384];
  const int swz = (blockIdx.x & 7) * 32 + (blockIdx.x >> 3);
  gemm64_body<1, 0>(At, Wvtb, Ftb, 1024, 1024, 1024, 0, 1024, swz >> 4,
                    swz & 15, 0, 1, 1.0f, shmem);
}

// ---------------------------------------------------------------------------
extern "C" void kernel_launch(void* const* d_in, const int* in_sizes, int n_in,
                              void* d_out, int out_size, void* d_ws,
                              size_t ws_size, hipStream_t stream) {
  const float* x = (const float*)d_in[0];
  const float* Wq = (const float*)d_in[1];
  const float* bq = (const float*)d_in[2];
  const float* Wk = (const float*)d_in[3];
  const float* bk = (const float*)d_in[4];
  const float* Wv = (const float*)d_in[5];
  const float* bv = (const float*)d_in[6];
  (void)in_sizes;
  (void)n_in;
  (void)out_size;
  (void)ws_size;

  char* ws = (char*)d_ws;
  const size_t MB = 1ull << 20;
  bf16* xb = (bf16*)(ws);                // [8192][1024], 16MB
  bf16* xt = (bf16*)(ws + 16 * MB);      // [1024][8192], 16MB
  float* SpG = (float*)(ws + 32 * MB);   // [8][1024][1024] f32, 32MB (tri)
  bf16* Wkext = (bf16*)(ws + 64 * MB);   // [1024][2048] ([Wk|Wk]), 4MB
  bf16* Wqx2 = (bf16*)(ws + 68 * MB);    // [1024][2048] ([Wq|Wq]), 4MB
  bf16* Wvtb = (bf16*)(ws + 72 * MB);    // [1024][1024] (Wv^T), 2MB
  bf16* Gext = (bf16*)(ws + 74 * MB);    // [1024][2048], 4MB
  bf16* T1x = (bf16*)(ws + 78 * MB);     // [1024][2048] (T1 z-concat), 4MB
  float* Stp = (float*)(ws + 82 * MB);   // [2][1024][1024] f32, 8MB
  bf16* At = (bf16*)(ws + 90 * MB);      // [1024][1024], 2MB
  bf16* Ftb = (bf16*)(ws + 92 * MB);     // [1024][1024], 2MB
  float* uw = (float*)(ws + 94 * MB);           // [2048]
  float* rv = (float*)(ws + 94 * MB + 16384);   // [1024]
  float* part = (float*)(ws + 95 * MB);         // [128][1024] f32, 512KB

  // 1. x -> xb, xt, part; weights -> Wqx2, Wkext, Wvtb (one kernel)
  pre_all<<<dim3(16, 176), 256, 0, stream>>>(
      x, Wq, Wk, Wv, (unsigned short*)xb, (unsigned short*)xt, part,
      (unsigned short*)Wqx2, (unsigned short*)Wkext, (unsigned short*)Wvtb);
  // 2. G = x^T x lower-triangle: TRI grid 288 (36 pairs x 8 K-chunks)
  gemm_nt<0, 0, 0, 0, 1><<<288, 256, 0, stream>>>(
      xt, xt, nullptr, SpG, 1024, 1024, 8192, 1024, 1.0f);
  // 3. middle chain: cooperative if supported, else 5-kernel fallback (R8)
  {
    const float* Sp_ = SpG;
    unsigned short* Gext_ = (unsigned short*)Gext;
    const float* part_ = part;
    const float* Wq_ = Wq;
    const float* Wk_ = Wk;
    float* uw_ = uw;
    const bf16* Wkext_ = Wkext;
    bf16* T1x_ = T1x;
    const bf16* Wqx2_ = Wqx2;
    float* Stp_ = Stp;
    const float* bq_ = bq;
    const float* bk_ = bk;
    const float* bv_ = bv;
    bf16* At_ = At;
    float* rv_ = rv;
    const bf16* Wvtb_ = Wvtb;
    bf16* Ftb_ = Ftb;
    void* args[] = {&Sp_, &Gext_, &part_, &Wq_, &Wk_, &uw_,
                    &Wkext_, &T1x_, &Wqx2_, &Stp_, &bq_, &bk_,
                    &bv_, &At_, &rv_, &Wvtb_, &Ftb_};
    hipError_t cerr = hipLaunchCooperativeKernel(coop_mid, dim3(512), dim3(256),
                                                 args, 0u, stream);
    if (cerr != hipSuccess) {
      k_gext_svuw<<<384, 256, 0, stream>>>(SpG, (unsigned short*)Gext, part, Wq,
                                           Wk, uw);
      k_t1<<<512, 256, 0, stream>>>(Wkext, Gext, T1x);
      k_st<<<512, 256, 0, stream>>>(T1x, Wqx2, Stp);
      k_softmax<<<512, 256, 0, stream>>>(Stp, uw, bq, bk, bv, At, rv);
      k_f<<<256, 256, 0, stream>>>(At, Wvtb, Ftb);
    }
  }
  // 4. out = x * F + 1*r^T : NT(xb, Ftb) + bias[col] -> f32 d_out
  gemm_nt<2, 0, 1, 0, 0><<<dim3(8, 64), 256, 0, stream>>>(
      xb, Ftb, rv, d_out, 8192, 1024, 1024, 1024, 1.0f);
}

// Round 12
// 103.031 us; speedup vs baseline: 5.3817x; 5.3817x over previous
//
#include <hip/hip_runtime.h>
#include <hip/hip_bf16.h>
#include <stdint.h>

using bf16 = __hip_bfloat16;
typedef __attribute__((ext_vector_type(8))) short bf16x8;
typedef __attribute__((ext_vector_type(4))) float f32x4;

// NOTE (R11 lesson): hipLaunchCooperativeKernel works on this harness, but
// cg::grid_group::sync() costs ~95us per sync on MI355X (cross-XCD L2
// flush for coherence). Kernel-boundary gaps are ~3.5us. Never grid-sync.

// ---------------------------------------------------------------------------
// helpers
// ---------------------------------------------------------------------------
__device__ __forceinline__ void gload_lds16(const void* g, void* l) {
  __builtin_amdgcn_global_load_lds(
      (__attribute__((address_space(1))) void*)(g),
      (__attribute__((address_space(3))) void*)(l), 16, 0, 0);
}

__device__ __forceinline__ unsigned short bf16_bits(float f) {
  bf16 b = __float2bfloat16(f);
  return *reinterpret_cast<unsigned short*>(&b);
}

__device__ __forceinline__ float b2f(unsigned short u) {
  union { unsigned int i; float f; } x;
  x.i = ((unsigned int)u) << 16;
  return x.f;
}

// ---------------------------------------------------------------------------
// pre_all: grid (16, 176).  (unchanged from R8)
// ---------------------------------------------------------------------------
__global__ __launch_bounds__(256) void pre_all(
    const float* __restrict__ x, const float* __restrict__ Wq,
    const float* __restrict__ Wk, const float* __restrict__ Wv,
    unsigned short* __restrict__ xb, unsigned short* __restrict__ xt,
    float* __restrict__ part, unsigned short* __restrict__ Wqx2,
    unsigned short* __restrict__ Wkext, unsigned short* __restrict__ Wvtb) {
  __shared__ unsigned short tile[64][79];
  __shared__ float cw[4][64];
  const int by = blockIdx.y;
  const int c0 = blockIdx.x * 64;
  const int tr = threadIdx.x >> 4;         // 0..15
  const int tc4 = (threadIdx.x & 15) * 4;  // 0,4,..,60

  if (by < 128) {
    const int r0 = by * 64;
    float ca0 = 0.f, ca1 = 0.f, ca2 = 0.f, ca3 = 0.f;
#pragma unroll
    for (int p = 0; p < 4; ++p) {
      const int r = p * 16 + tr;
      float4 f =
          *reinterpret_cast<const float4*>(x + (size_t)(r0 + r) * 1024 + c0 + tc4);
      unsigned short u0 = bf16_bits(f.x), u1 = bf16_bits(f.y);
      unsigned short u2 = bf16_bits(f.z), u3 = bf16_bits(f.w);
      ushort4 u = {u0, u1, u2, u3};
      *reinterpret_cast<ushort4*>(xb + (size_t)(r0 + r) * 1024 + c0 + tc4) = u;
      tile[r][tc4] = u0;
      tile[r][tc4 + 1] = u1;
      tile[r][tc4 + 2] = u2;
      tile[r][tc4 + 3] = u3;
      ca0 += f.x;
      ca1 += f.y;
      ca2 += f.z;
      ca3 += f.w;
    }
    ca0 += __shfl_xor(ca0, 16); ca0 += __shfl_xor(ca0, 32);
    ca1 += __shfl_xor(ca1, 16); ca1 += __shfl_xor(ca1, 32);
    ca2 += __shfl_xor(ca2, 16); ca2 += __shfl_xor(ca2, 32);
    ca3 += __shfl_xor(ca3, 16); ca3 += __shfl_xor(ca3, 32);
    const int lane = threadIdx.x & 63, wv = threadIdx.x >> 6;
    if (lane < 16) {
      cw[wv][lane * 4] = ca0;
      cw[wv][lane * 4 + 1] = ca1;
      cw[wv][lane * 4 + 2] = ca2;
      cw[wv][lane * 4 + 3] = ca3;
    }
    __syncthreads();
    if (threadIdx.x < 64) {
      float s = cw[0][threadIdx.x] + cw[1][threadIdx.x] + cw[2][threadIdx.x] +
                cw[3][threadIdx.x];
      part[(size_t)by * 1024 + c0 + threadIdx.x] = s;
    }
#pragma unroll
    for (int p = 0; p < 4; ++p) {
      const int c = p * 16 + tr;
      ushort4 u = {tile[tc4][c], tile[tc4 + 1][c], tile[tc4 + 2][c],
                   tile[tc4 + 3][c]};
      *reinterpret_cast<ushort4*>(xt + (size_t)(c0 + c) * 8192 + r0 + tc4) = u;
    }
  } else {
    const int w = by - 128;
    const int widx = w >> 4;          // 0=Wq,1=Wk,2=Wv
    const int r0 = (w & 15) * 64;
    if (widx < 2) {
      const float* W = (widx == 0) ? Wq : Wk;
      unsigned short* out = (widx == 0) ? Wqx2 : Wkext;
#pragma unroll
      for (int p = 0; p < 4; ++p) {
        const int r = r0 + p * 16 + tr;
        float4 f =
            *reinterpret_cast<const float4*>(W + (size_t)r * 1024 + c0 + tc4);
        ushort4 u = {bf16_bits(f.x), bf16_bits(f.y), bf16_bits(f.z),
                     bf16_bits(f.w)};
        *reinterpret_cast<ushort4*>(out + (size_t)r * 2048 + c0 + tc4) = u;
        *reinterpret_cast<ushort4*>(out + (size_t)r * 2048 + 1024 + c0 + tc4) = u;
      }
    } else {
#pragma unroll
      for (int p = 0; p < 4; ++p) {
        const int r = p * 16 + tr;
        float4 f = *reinterpret_cast<const float4*>(Wv + (size_t)(r0 + r) * 1024 +
                                                    c0 + tc4);
        tile[r][tc4] = bf16_bits(f.x);
        tile[r][tc4 + 1] = bf16_bits(f.y);
        tile[r][tc4 + 2] = bf16_bits(f.z);
        tile[r][tc4 + 3] = bf16_bits(f.w);
      }
      __syncthreads();
#pragma unroll
      for (int p = 0; p < 4; ++p) {
        const int c = p * 16 + tr;
        ushort4 u = {tile[tc4][c], tile[tc4 + 1][c], tile[tc4 + 2][c],
                     tile[tc4 + 3][c]};
        *reinterpret_cast<ushort4*>(Wvtb + (size_t)(c0 + c) * 1024 + r0 + tc4) = u;
      }
    }
  }
}

// ---------------------------------------------------------------------------
// NT GEMM, 2-phase double-buffered 128x128 (unchanged from R8): G (TRI) + out.
// ---------------------------------------------------------------------------
template <int BIAS_MODE, int OUT_BF16, int XCD_SWZ, int CONCAT, int TRI>
__global__ __launch_bounds__(256, 2) void gemm_nt(
    const bf16* __restrict__ A, const bf16* __restrict__ B,
    const float* __restrict__ bias, void* __restrict__ Cout, int M, int N,
    int K, int kChunk, float scale) {
  __shared__ __align__(128) char lds[65536];  // A: [2][16KB] @0, B: @32768
  const int tid = threadIdx.x;
  const int lane = tid & 63;
  const int wv = tid >> 6;
  const int wm = wv >> 1, wn = wv & 1;

  int mt, nt, zz;
  if (TRI) {
    const int lin = blockIdx.x;
    zz = lin & 7;            // one K-chunk per XCD
    const int p = lin >> 3;  // 0..35 triangle pair
    int ii = 0;
    while ((ii + 1) * (ii + 2) / 2 <= p) ++ii;
    mt = ii;
    nt = p - ii * (ii + 1) / 2;
  } else if (XCD_SWZ) {
    int lin = blockIdx.y * gridDim.x + blockIdx.x;
    int cpx = (gridDim.x * gridDim.y) >> 3;  // nwg % 8 == 0 required
    int swz = (lin & 7) * cpx + (lin >> 3);
    nt = swz % gridDim.x;
    mt = swz / gridDim.x;
    zz = blockIdx.z;
  } else {
    nt = blockIdx.x;
    mt = blockIdx.y;
    zz = blockIdx.z;
  }
  const int m0 = mt * 128, n0 = nt * 128;
  const int kBegin = zz * kChunk;

  const char* srcA[4];
  const char* srcB[4];
  int dstOff[4];
#pragma unroll
  for (int t = 0; t < 4; ++t) {
    int o = wv * 4096 + t * 1024 + lane * 16;  // linear LDS byte offset
    int row = o >> 7;                          // tile row (128B per row)
    int gcb = (o & 127) ^ ((row & 7) << 4);    // inverse-swizzled global col
    srcA[t] = (const char*)A + ((size_t)(m0 + row) * K + kBegin) * 2 + gcb;
    srcB[t] = (const char*)B + ((size_t)(n0 + row) * K + kBegin) * 2 + gcb;
    dstOff[t] = wv * 4096 + t * 1024;
  }

  const int xorv = (lane & 7) << 4;
  const int rowOff = (lane & 15) * 128;
  const int colHi = (lane >> 4) << 4;

  // prologue: stage tile 0 into buf 0
#pragma unroll
  for (int t = 0; t < 4; ++t) gload_lds16(srcA[t], lds + dstOff[t]);
#pragma unroll
  for (int t = 0; t < 4; ++t) gload_lds16(srcB[t], lds + 32768 + dstOff[t]);
#pragma unroll
  for (int t = 0; t < 4; ++t) {
    srcA[t] += 128;
    srcB[t] += 128;
  }
  __syncthreads();

  f32x4 acc[4][4] = {};
  const int nk = kChunk >> 6;
  int cur = 0;
  for (int kt = 0; kt < nk; ++kt) {
    if (kt + 1 < nk) {  // prefetch next tile into the other buffer
      const int nb = (cur ^ 1) * 16384;
#pragma unroll
      for (int t = 0; t < 4; ++t) gload_lds16(srcA[t], lds + nb + dstOff[t]);
#pragma unroll
      for (int t = 0; t < 4; ++t)
        gload_lds16(srcB[t], lds + 32768 + nb + dstOff[t]);
#pragma unroll
      for (int t = 0; t < 4; ++t) {
        srcA[t] += 128;
        srcB[t] += 128;
      }
    }
    const char* baseA = lds + cur * 16384;
    const char* baseB = lds + 32768 + cur * 16384;
#pragma unroll
    for (int h = 0; h < 2; ++h) {
      const int kk64 = h * 64;
      bf16x8 af[4], bfr[4];
#pragma unroll
      for (int f = 0; f < 4; ++f)
        af[f] = *reinterpret_cast<const bf16x8*>(
            baseA + ((wm * 64 + f * 16) * 128) + rowOff + ((kk64 + colHi) ^ xorv));
#pragma unroll
      for (int f = 0; f < 4; ++f)
        bfr[f] = *reinterpret_cast<const bf16x8*>(
            baseB + ((wn * 64 + f * 16) * 128) + rowOff + ((kk64 + colHi) ^ xorv));
      __builtin_amdgcn_s_setprio(1);
#pragma unroll
      for (int m = 0; m < 4; ++m)
#pragma unroll
        for (int n = 0; n < 4; ++n)
          acc[m][n] = __builtin_amdgcn_mfma_f32_16x16x32_bf16(af[m], bfr[n],
                                                              acc[m][n], 0, 0, 0);
      __builtin_amdgcn_s_setprio(0);
    }
    __syncthreads();  // staged loads drained; all waves done reading cur
    cur ^= 1;
  }

  // epilogue: C/D layout col=lane&15, row=(lane>>4)*4+r (guide §3, m89)
  const int ldC = CONCAT ? (int)(gridDim.z * N) : N;
  const int cOff = CONCAT ? (int)(zz * N) : 0;
  char* Cbase = (char*)Cout;
  if (!CONCAT) Cbase += (size_t)zz * M * N * (OUT_BF16 ? 2 : 4);
#pragma unroll
  for (int m = 0; m < 4; ++m) {
    const int grow = m0 + wm * 64 + m * 16 + ((lane >> 4) << 2);
#pragma unroll
    for (int n = 0; n < 4; ++n) {
      const int gcol = n0 + wn * 64 + n * 16 + (lane & 15);
#pragma unroll
      for (int r = 0; r < 4; ++r) {
        float v = acc[m][n][r] * scale;
        if (BIAS_MODE == 2) v += bias[gcol];
        if (OUT_BF16)
          ((bf16*)Cbase)[(size_t)(grow + r) * ldC + cOff + gcol] =
              __float2bfloat16(v);
        else
          ((float*)Cbase)[(size_t)(grow + r) * ldC + cOff + gcol] = v;
      }
    }
  }
}

// ---------------------------------------------------------------------------
// 64x64 NT GEMM body, BK=128 (A tile [64][256B] 16KB @0, B @16384; 32KB LDS).
// Halves the serial K-step count vs BK=64 for the latency-bound small GEMMs.
// Swizzle re-derived for 256B rows: same (row&7)<<4 XOR (bits 4-6), bijective
// within the row; lanes 0-15 hit 8 distinct 16B slots -> 2-way free (m136).
// K accumulation order identical to BK=64 (kt*128 + h*32 ascending) ->
// bit-identical results. ZCAT: C[row][zz*N+col], ld gridZ*N.
// ---------------------------------------------------------------------------
template <int OUT_BF16, int ZCAT>
__device__ __forceinline__ void gemm64_body(const bf16* A, const bf16* B,
                                            void* Cout, int M, int N, int K,
                                            int kBegin, int kChunk, int mt,
                                            int nt, int zz, int gridZ,
                                            float scale, char* lds) {
  const int tid = threadIdx.x;
  const int lane = tid & 63;
  const int wv = tid >> 6;
  const int wm = wv >> 1, wn = wv & 1;
  const int m0 = mt * 64, n0 = nt * 64;

  const char* srcA[4];
  const char* srcB[4];
  int dstOff[4];
#pragma unroll
  for (int t = 0; t < 4; ++t) {
    int o = wv * 4096 + t * 1024 + lane * 16;  // linear LDS byte offset
    int row = o >> 8;                          // tile row (256B per row)
    int gcb = (o & 255) ^ ((row & 7) << 4);    // inverse-swizzled global col
    srcA[t] = (const char*)A + ((size_t)(m0 + row) * K + kBegin) * 2 + gcb;
    srcB[t] = (const char*)B + ((size_t)(n0 + row) * K + kBegin) * 2 + gcb;
    dstOff[t] = wv * 4096 + t * 1024;
  }

  const int xorv = (lane & 7) << 4;
  const int rowOff = (lane & 15) * 256;
  const int colHi = (lane >> 4) << 4;

  f32x4 acc[2][2] = {};
  const int nk = kChunk >> 7;  // BK=128
  for (int kt = 0; kt < nk; ++kt) {
#pragma unroll
    for (int t = 0; t < 4; ++t) gload_lds16(srcA[t], lds + dstOff[t]);
#pragma unroll
    for (int t = 0; t < 4; ++t) gload_lds16(srcB[t], lds + 16384 + dstOff[t]);
#pragma unroll
    for (int t = 0; t < 4; ++t) {
      srcA[t] += 256;  // advance 128 bf16 in k
      srcB[t] += 256;
    }
    __syncthreads();
#pragma unroll
    for (int h = 0; h < 4; ++h) {
      const int kk = h * 64;  // byte offset of K sub-block (32 elems)
      bf16x8 af[2], bfr[2];
#pragma unroll
      for (int f = 0; f < 2; ++f)
        af[f] = *reinterpret_cast<const bf16x8*>(
            lds + ((wm * 32 + f * 16) * 256) + rowOff + ((kk + colHi) ^ xorv));
#pragma unroll
      for (int f = 0; f < 2; ++f)
        bfr[f] = *reinterpret_cast<const bf16x8*>(
            lds + 16384 + ((wn * 32 + f * 16) * 256) + rowOff +
            ((kk + colHi) ^ xorv));
      __builtin_amdgcn_s_setprio(1);
#pragma unroll
      for (int m = 0; m < 2; ++m)
#pragma unroll
        for (int n = 0; n < 2; ++n)
          acc[m][n] = __builtin_amdgcn_mfma_f32_16x16x32_bf16(af[m], bfr[n],
                                                              acc[m][n], 0, 0, 0);
      __builtin_amdgcn_s_setprio(0);
    }
    __syncthreads();
  }

  const int ldC = ZCAT ? gridZ * N : N;
  const int cOff = ZCAT ? zz * N : 0;
  char* Cbase = (char*)Cout;
  if (!ZCAT) Cbase += (size_t)zz * M * N * (OUT_BF16 ? 2 : 4);
#pragma unroll
  for (int m = 0; m < 2; ++m) {
    const int grow = m0 + wm * 32 + m * 16 + ((lane >> 4) << 2);
#pragma unroll
    for (int n = 0; n < 2; ++n) {
      const int gcol = n0 + wn * 32 + n * 16 + (lane & 15);
#pragma unroll
      for (int r = 0; r < 4; ++r) {
        float v = acc[m][n][r] * scale;
        if (OUT_BF16)
          ((bf16*)Cbase)[(size_t)(grow + r) * ldC + cOff + gcol] =
              __float2bfloat16(v);
        else
          ((float*)Cbase)[(size_t)(grow + r) * ldC + cOff + gcol] = v;
      }
    }
  }
}

// ---------------------------------------------------------------------------
// phase bodies (bit-identical math to R8)
// ---------------------------------------------------------------------------
__device__ __forceinline__ void phase_gext(const float* Sp,
                                           unsigned short* Gext, int bx,
                                           int tid, char* shmem) {
  float(*tf)[65] = reinterpret_cast<float(*)[65]>(shmem);
  const int ti = bx >> 4, tj = bx & 15;
  const bool mirror = (ti >> 1) < (tj >> 1);
  const int si = mirror ? tj : ti, sj = mirror ? ti : tj;
  const int r = tid >> 4, c4 = (tid & 15) * 4;
#pragma unroll
  for (int pass = 0; pass < 4; ++pass) {
    const int row = pass * 16 + r;
    float g0 = 0.f, g1 = 0.f, g2 = 0.f, g3 = 0.f;
#pragma unroll
    for (int z = 0; z < 8; ++z) {
      float4 f = *reinterpret_cast<const float4*>(
          Sp + ((size_t)z << 20) + (size_t)(si * 64 + row) * 1024 + sj * 64 + c4);
      g0 += f.x;
      g1 += f.y;
      g2 += f.z;
      g3 += f.w;
    }
    if (!mirror) {
      ushort4 hi, lo;
      unsigned short bb;
      bb = bf16_bits(g0); hi.x = bb; lo.x = bf16_bits(g0 - b2f(bb));
      bb = bf16_bits(g1); hi.y = bb; lo.y = bf16_bits(g1 - b2f(bb));
      bb = bf16_bits(g2); hi.z = bb; lo.z = bf16_bits(g2 - b2f(bb));
      bb = bf16_bits(g3); hi.w = bb; lo.w = bf16_bits(g3 - b2f(bb));
      const size_t base = (size_t)(ti * 64 + row) * 2048 + tj * 64 + c4;
      *reinterpret_cast<ushort4*>(Gext + base) = hi;
      *reinterpret_cast<ushort4*>(Gext + base + 1024) = lo;
    } else {
      tf[row][c4] = g0;
      tf[row][c4 + 1] = g1;
      tf[row][c4 + 2] = g2;
      tf[row][c4 + 3] = g3;
    }
  }
  if (mirror) {
    __syncthreads();
#pragma unroll
    for (int pass = 0; pass < 4; ++pass) {
      const int crow = pass * 16 + r;
      ushort4 hi, lo;
      unsigned short bb;
      float g;
      g = tf[c4][crow];     bb = bf16_bits(g); hi.x = bb; lo.x = bf16_bits(g - b2f(bb));
      g = tf[c4 + 1][crow]; bb = bf16_bits(g); hi.y = bb; lo.y = bf16_bits(g - b2f(bb));
      g = tf[c4 + 2][crow]; bb = bf16_bits(g); hi.z = bb; lo.z = bf16_bits(g - b2f(bb));
      g = tf[c4 + 3][crow]; bb = bf16_bits(g); hi.w = bb; lo.w = bf16_bits(g - b2f(bb));
      const size_t base = (size_t)(ti * 64 + crow) * 2048 + tj * 64 + c4;
      *reinterpret_cast<ushort4*>(Gext + base) = hi;
      *reinterpret_cast<ushort4*>(Gext + base + 1024) = lo;
    }
  }
}

__device__ __forceinline__ void phase_svuw(const float* part, const float* Wq,
                                           const float* Wk, float* uw, int bxm,
                                           int tid, char* shmem) {
  float* svl = reinterpret_cast<float*>(shmem);
  float4 a = {0.f, 0.f, 0.f, 0.f};
  for (int p = 0; p < 128; ++p) {
    float4 f = *reinterpret_cast<const float4*>(part + (size_t)p * 1024 + tid * 4);
    a.x += f.x;
    a.y += f.y;
    a.z += f.z;
    a.w += f.w;
  }
  *reinterpret_cast<float4*>(svl + tid * 4) = a;
  __syncthreads();
  const int lane = tid & 63, wv = tid >> 6;
  const int lane16 = lane & 15, rsub = lane >> 4;
  const int row = bxm * 16 + wv * 4 + rsub;
  const float* W = (row < 1024) ? (Wq + (size_t)row * 1024)
                                : (Wk + (size_t)(row - 1024) * 1024);
  float acc = 0.f;
#pragma unroll
  for (int q = 0; q < 16; ++q) {
    const int c = (lane16 + q * 16) * 4;
    float4 wv4 = *reinterpret_cast<const float4*>(W + c);
    float4 s4 = *reinterpret_cast<const float4*>(svl + c);
    acc += wv4.x * s4.x + wv4.y * s4.y + wv4.z * s4.z + wv4.w * s4.w;
  }
#pragma unroll
  for (int off = 1; off < 16; off <<= 1) acc += __shfl_xor(acc, off);
  if (lane16 == 0) uw[row] = acc;
}

__device__ __forceinline__ void phase_softmax(const float* Stp, const float* uw,
                                              const float* bq, const float* bk,
                                              const float* bv, bf16* At,
                                              float* rv, int j, int tid,
                                              float* red) {
  const int lane = tid & 63, wv = tid >> 6;
  __syncthreads();  // protect red[] reuse across consecutive rows
  const float a1 = bk[j];
  const float a2 = uw[1024 + j] + 8192.0f * a1;
  const float norm = 0.03125f;  // 1/sqrt(1024)
  float v[4];
#pragma unroll
  for (int t = 0; t < 4; ++t) {
    const int i = tid + 256 * t;
    float s = Stp[(size_t)j * 1024 + i] + Stp[(1ull << 20) + (size_t)j * 1024 + i];
    v[t] = norm * (s + a1 * uw[i] + a2 * bq[i]);
  }
  float m = fmaxf(fmaxf(v[0], v[1]), fmaxf(v[2], v[3]));
#pragma unroll
  for (int off = 32; off; off >>= 1) m = fmaxf(m, __shfl_xor(m, off));
  if (lane == 0) red[wv] = m;
  __syncthreads();
  m = fmaxf(fmaxf(red[0], red[1]), fmaxf(red[2], red[3]));
  float p[4], s = 0.f, pr = 0.f;
#pragma unroll
  for (int t = 0; t < 4; ++t) {
    p[t] = __expf(v[t] - m);
    s += p[t];
    pr += p[t] * bv[tid + 256 * t];
  }
#pragma unroll
  for (int off = 32; off; off >>= 1) {
    s += __shfl_xor(s, off);
    pr += __shfl_xor(pr, off);
  }
  if (lane == 0) {
    red[4 + wv] = s;
    red[8 + wv] = pr;
  }
  __syncthreads();
  const float inv = 1.f / (red[4] + red[5] + red[6] + red[7]);
#pragma unroll
  for (int t = 0; t < 4; ++t)
    At[(size_t)j * 1024 + tid + 256 * t] = __float2bfloat16(p[t] * inv);
  if (tid == 0) rv[j] = (red[8] + red[9] + red[10] + red[11]) * inv;
}

// ---------------------------------------------------------------------------
// mid-chain kernels (R8-equivalent node structure)
// ---------------------------------------------------------------------------
__global__ __launch_bounds__(256) void k_gext_svuw(
    const float* __restrict__ Sp, unsigned short* __restrict__ Gext,
    const float* __restrict__ part, const float* __restrict__ Wq,
    const float* __restrict__ Wk, float* __restrict__ uw) {
  __shared__ __align__(128) char shmem[16640];
  if (blockIdx.x < 256)
    phase_gext(Sp, Gext, blockIdx.x, threadIdx.x, shmem);
  else
    phase_svuw(part, Wq, Wk, uw, blockIdx.x - 256, threadIdx.x, shmem);
}

__global__ __launch_bounds__(256, 4) void k_t1(const bf16* __restrict__ Wkext,
                                               const bf16* __restrict__ Gext,
                                               bf16* __restrict__ T1x) {
  __shared__ __align__(128) char shmem[32768];
  const int z = blockIdx.x >> 8;
  const int lin = blockIdx.x & 255;
  const int swz = (lin & 7) * 32 + (lin >> 3);
  gemm64_body<1, 1>(Wkext, Gext, T1x, 1024, 1024, 2048, z * 1024, 1024,
                    swz >> 4, swz & 15, z, 2, 1.0f, shmem);
}

__global__ __launch_bounds__(256, 4) void k_st(const bf16* __restrict__ T1x,
                                               const bf16* __restrict__ Wqx2,
                                               float* __restrict__ Stp) {
  __shared__ __align__(128) char shmem[32768];
  const int z = blockIdx.x >> 8;
  const int lin = blockIdx.x & 255;
  const int swz = (lin & 7) * 32 + (lin >> 3);
  gemm64_body<0, 0>(T1x, Wqx2, Stp, 1024, 1024, 2048, z * 1024, 1024, swz >> 4,
                    swz & 15, z, 2, 1.0f, shmem);
}

__global__ __launch_bounds__(256) void k_softmax(
    const float* __restrict__ Stp, const float* __restrict__ uw,
    const float* __restrict__ bq, const float* __restrict__ bk,
    const float* __restrict__ bv, bf16* __restrict__ At,
    float* __restrict__ rv) {
  __shared__ float red[12];
  phase_softmax(Stp, uw, bq, bk, bv, At, rv, blockIdx.x * 2, threadIdx.x, red);
  phase_softmax(Stp, uw, bq, bk, bv, At, rv, blockIdx.x * 2 + 1, threadIdx.x,
                red);
}

__global__ __launch_bounds__(256, 4) void k_f(const bf16* __restrict__ At,
                                              const bf16* __restrict__ Wvtb,
                                              bf16* __restrict__ Ftb) {
  __shared__ __align__(128) char shmem[32768];
  const int swz = (blockIdx.x & 7) * 32 + (blockIdx.x >> 3);
  gemm64_body<1, 0>(At, Wvtb, Ftb, 1024, 1024, 1024, 0, 1024, swz >> 4,
                    swz & 15, 0, 1, 1.0f, shmem);
}

// ---------------------------------------------------------------------------
extern "C" void kernel_launch(void* const* d_in, const int* in_sizes, int n_in,
                              void* d_out, int out_size, void* d_ws,
                              size_t ws_size, hipStream_t stream) {
  const float* x = (const float*)d_in[0];
  const float* Wq = (const float*)d_in[1];
  const float* bq = (const float*)d_in[2];
  const float* Wk = (const float*)d_in[3];
  const float* bk = (const float*)d_in[4];
  const float* Wv = (const float*)d_in[5];
  const float* bv = (const float*)d_in[6];
  (void)in_sizes;
  (void)n_in;
  (void)out_size;
  (void)ws_size;

  char* ws = (char*)d_ws;
  const size_t MB = 1ull << 20;
  bf16* xb = (bf16*)(ws);                // [8192][1024], 16MB
  bf16* xt = (bf16*)(ws + 16 * MB);      // [1024][8192], 16MB
  float* SpG = (float*)(ws + 32 * MB);   // [8][1024][1024] f32, 32MB (tri)
  bf16* Wkext = (bf16*)(ws + 64 * MB);   // [1024][2048] ([Wk|Wk]), 4MB
  bf16* Wqx2 = (bf16*)(ws + 68 * MB);    // [1024][2048] ([Wq|Wq]), 4MB
  bf16* Wvtb = (bf16*)(ws + 72 * MB);    // [1024][1024] (Wv^T), 2MB
  bf16* Gext = (bf16*)(ws + 74 * MB);    // [1024][2048], 4MB
  bf16* T1x = (bf16*)(ws + 78 * MB);     // [1024][2048] (T1 z-concat), 4MB
  float* Stp = (float*)(ws + 82 * MB);   // [2][1024][1024] f32, 8MB
  bf16* At = (bf16*)(ws + 90 * MB);      // [1024][1024], 2MB
  bf16* Ftb = (bf16*)(ws + 92 * MB);     // [1024][1024], 2MB
  float* uw = (float*)(ws + 94 * MB);           // [2048]
  float* rv = (float*)(ws + 94 * MB + 16384);   // [1024]
  float* part = (float*)(ws + 95 * MB);         // [128][1024] f32, 512KB

  // 1. x -> xb, xt, part; weights -> Wqx2, Wkext, Wvtb (one kernel)
  pre_all<<<dim3(16, 176), 256, 0, stream>>>(
      x, Wq, Wk, Wv, (unsigned short*)xb, (unsigned short*)xt, part,
      (unsigned short*)Wqx2, (unsigned short*)Wkext, (unsigned short*)Wvtb);
  // 2. G = x^T x lower-triangle: TRI grid 288 (36 pairs x 8 K-chunks)
  gemm_nt<0, 0, 0, 0, 1><<<288, 256, 0, stream>>>(
      xt, xt, nullptr, SpG, 1024, 1024, 8192, 1024, 1.0f);
  // 3. Gext assembly (mirror+residual) + uw = [Wq;Wk].colsum(x)
  k_gext_svuw<<<384, 256, 0, stream>>>(SpG, (unsigned short*)Gext, part, Wq,
                                       Wk, uw);
  // 4. T1 = Wk*G: K=2048 split-K=2, bf16 col-concat -> T1x[1024][2048]
  k_t1<<<512, 256, 0, stream>>>(Wkext, Gext, T1x);
  // 5. St = T1x * Wqx2^T (K=2048), split-K=2 -> f32 partials
  k_st<<<512, 256, 0, stream>>>(T1x, Wqx2, Stp);
  // 6. atten^T = softmax(sum partials + corrections); r = atten^T.bv
  k_softmax<<<512, 256, 0, stream>>>(Stp, uw, bq, bk, bv, At, rv);
  // 7. F^T = At * Wvt^T -> bf16
  k_f<<<256, 256, 0, stream>>>(At, Wvtb, Ftb);
  // 8. out = x * F + 1*r^T : NT(xb, Ftb) + bias[col] -> f32 d_out
  gemm_nt<2, 0, 1, 0, 0><<<dim3(8, 64), 256, 0, stream>>>(
      xb, Ftb, rv, d_out, 8192, 1024, 1024, 1024, 1.0f);
}